// Round 1
// baseline (333.287 us; speedup 1.0000x reference)
//
#include <hip/hip_runtime.h>
#include <cmath>

// Conductance-based LIF scan: T=512 steps, N=65536 neurons.
// One thread per neuron; serial loop over T (carried state), coalesced
// loads/stores at t*N + n. Memory-bound: ~640 MiB traffic/call.
//
// Numerics: must match numpy f32 reference closely enough that NO spike
// flips (spike output threshold is 0.02 absmax => exact spike match).
// => use __f{mul,add,sub}_rn to block FMA contraction, __fdiv_rn, and a
// correctly-rounded f32 exp via double exp. gA is identically zero
// (ADAPT_INC==0, gA0==0) so it is elided exactly.

__global__ __launch_bounds__(256, 1) void lif_scan(
    const float* __restrict__ g_exc,
    const float* __restrict__ g_inh,
    const float* __restrict__ noise,
    const float* __restrict__ v_th,
    const float* __restrict__ tau_ref,
    float* __restrict__ out_spk,   // d_out[0 .. T*N)
    float* __restrict__ out_mem,   // d_out[T*N .. 2*T*N)
    int N, int T,
    float cGE, float cGI, float cALPHA, float cSIGMA)
{
    const int n = blockIdx.x * blockDim.x + threadIdx.x;
    if (n >= N) return;

    const float vth = v_th[n];
    const float trf = tau_ref[n];

    float v = 0.0f, gE = 0.0f, gI = 0.0f, ref = 0.0f, ou = 0.0f;

    // unroll 8: lets the compiler keep ~24 independent global loads in
    // flight per wave (only 1 wave/SIMD at this grid, so ILP must hide
    // HBM latency).
    #pragma unroll 8
    for (int t = 0; t < T; ++t) {
        const size_t off = (size_t)t * (size_t)N + (size_t)n;
        const float ge_in = g_exc[off];
        const float gi_in = g_inh[off];
        const float z     = noise[off];

        // conductance decay + input (separately rounded, like numpy)
        gE = __fadd_rn(__fmul_rn(gE, cGE), ge_in);
        gI = __fadd_rn(__fmul_rn(gI, cGI), gi_in);

        // g_tot_rel = ((1 + gE) + gI) + gA, gA == 0 exactly
        const float gt  = __fadd_rn(__fadd_rn(1.0f, gE), gI);
        // numerator = (E_L + gE*E_E) + gI*E_I  (+ gA*E_ADAPT == +0)
        const float num = __fadd_rn(__fmul_rn(gE, 3.0f), __fmul_rn(gI, -0.5f));
        const float vinf = __fdiv_rn(num, gt);

        // decay = exp(-0.05 * gt), correctly rounded f32 via double exp
        const float darg = __fmul_rn(-0.05f, gt);
        const float decay = (float)exp((double)darg);

        // v = vinf + (v - vinf) * decay
        v = __fadd_rn(vinf, __fmul_rn(__fsub_rn(v, vinf), decay));

        // OU noise
        ou = __fadd_rn(__fmul_rn(ou, cALPHA), __fmul_rn(cSIGMA, z));
        v = __fadd_rn(v, ou);

        // refractory clamp
        const bool in_ref = (ref > 0.0f);
        if (in_ref) v = 0.0f;

        // spike + reset + refractory restart
        const bool spike = (v >= vth) && (!in_ref);
        if (spike) v = 0.0f;
        ref = spike ? trf : fmaxf(__fsub_rn(ref, 1.0f), 0.0f);

        out_spk[off] = spike ? 1.0f : 0.0f;
        out_mem[off] = v;
    }
}

extern "C" void kernel_launch(void* const* d_in, const int* in_sizes, int n_in,
                              void* d_out, int out_size, void* d_ws, size_t ws_size,
                              hipStream_t stream) {
    const float* g_exc   = (const float*)d_in[0];
    const float* g_inh   = (const float*)d_in[1];
    const float* noise   = (const float*)d_in[2];
    const float* v_th    = (const float*)d_in[3];
    const float* tau_ref = (const float*)d_in[4];

    const int N = in_sizes[3];            // 65536
    const int T = in_sizes[0] / N;        // 512

    float* out_spk = (float*)d_out;
    float* out_mem = (float*)d_out + (size_t)T * (size_t)N;

    // Constants computed in double exactly as the Python reference does,
    // then rounded once to f32 (same as float(np.exp(...))).
    const double ge_decay = exp(-1.0 / 5.0);    // exp(-DT/TAU_E)
    const double gi_decay = exp(-1.0 / 10.0);   // exp(-DT/TAU_I)
    const double ou_alpha = exp(-1.0 / 5.0);    // exp(-DT/NOISE_TAU)
    const double ou_sigma = 0.02 * sqrt(1.0 - ou_alpha * ou_alpha);

    const int block = 256;
    const int grid = (N + block - 1) / block;   // 256 blocks = 1024 waves
    lif_scan<<<grid, block, 0, stream>>>(
        g_exc, g_inh, noise, v_th, tau_ref, out_spk, out_mem,
        N, T,
        (float)ge_decay, (float)gi_decay, (float)ou_alpha, (float)ou_sigma);
}

// Round 2
// 128.056 us; speedup vs baseline: 2.6027x; 2.6027x over previous
//
#include <hip/hip_runtime.h>
#include <cmath>

// Conductance-based LIF scan: T=512 steps, N=65536 neurons.
// One thread per neuron (1024 waves = 1 wave/SIMD -> no TLP), so HBM
// latency must be hidden with ILP: explicit register-level double-buffered
// prefetch of D=8 steps (3 floats/step) per thread.
//
// Numerics identical to the passing R1 kernel: __f{mul,add,sub}_rn to block
// FMA contraction, __fdiv_rn, correctly-rounded f32 exp via double exp.
// gA is identically zero (ADAPT_INC==0) and elided exactly.

#ifndef PFD
#define PFD 8   // prefetch depth (steps per register block)
#endif

__global__ __launch_bounds__(256, 1) void lif_scan(
    const float* __restrict__ g_exc,
    const float* __restrict__ g_inh,
    const float* __restrict__ noise,
    const float* __restrict__ v_th,
    const float* __restrict__ tau_ref,
    float* __restrict__ out_spk,   // d_out[0 .. T*N)
    float* __restrict__ out_mem,   // d_out[T*N .. 2*T*N)
    int N, int T,
    float cGE, float cGI, float cALPHA, float cSIGMA)
{
    const int n = blockIdx.x * blockDim.x + threadIdx.x;
    if (n >= N) return;

    const float vth = v_th[n];
    const float trf = tau_ref[n];

    float v = 0.0f, gE = 0.0f, gI = 0.0f, ref = 0.0f, ou = 0.0f;

    const float* __restrict__ pge = g_exc + n;
    const float* __restrict__ pgi = g_inh + n;
    const float* __restrict__ pz  = noise + n;

    // one simulation step (identical arithmetic/order to R1 kernel)
    auto step = [&](float ge_in, float gi_in, float z, int tt) {
        gE = __fadd_rn(__fmul_rn(gE, cGE), ge_in);
        gI = __fadd_rn(__fmul_rn(gI, cGI), gi_in);

        const float gt  = __fadd_rn(__fadd_rn(1.0f, gE), gI);
        const float num = __fadd_rn(__fmul_rn(gE, 3.0f), __fmul_rn(gI, -0.5f));
        const float vinf = __fdiv_rn(num, gt);

        const float darg = __fmul_rn(-0.05f, gt);
        const float decay = (float)exp((double)darg);

        v = __fadd_rn(vinf, __fmul_rn(__fsub_rn(v, vinf), decay));

        ou = __fadd_rn(__fmul_rn(ou, cALPHA), __fmul_rn(cSIGMA, z));
        v = __fadd_rn(v, ou);

        const bool in_ref = (ref > 0.0f);
        if (in_ref) v = 0.0f;

        const bool spike = (v >= vth) && (!in_ref);
        if (spike) v = 0.0f;
        ref = spike ? trf : fmaxf(__fsub_rn(ref, 1.0f), 0.0f);

        const size_t off = (size_t)tt * (size_t)N + (size_t)n;
        __builtin_nontemporal_store(spike ? 1.0f : 0.0f, out_spk + off);
        __builtin_nontemporal_store(v, out_mem + off);
    };

    float Age[PFD], Agi[PFD], Az[PFD];
    float Bge[PFD], Bgi[PFD], Bz[PFD];

    // prime buffer A with steps 0..PFD-1
    #pragma unroll
    for (int i = 0; i < PFD; ++i) {
        const size_t off = (size_t)i * (size_t)N;
        Age[i] = pge[off]; Agi[i] = pgi[off]; Az[i] = pz[off];
    }

    // main loop: 2*PFD steps per iteration, ping-pong A/B register blocks
    for (int t = 0; t < T; t += 2 * PFD) {
        // issue loads for steps t+PFD .. t+2*PFD-1 into B (overlap with A compute)
        #pragma unroll
        for (int i = 0; i < PFD; ++i) {
            int tp = t + PFD + i; tp = tp < T ? tp : T - 1;  // clamp (tail-safe)
            const size_t off = (size_t)tp * (size_t)N;
            Bge[i] = pge[off]; Bgi[i] = pgi[off]; Bz[i] = pz[off];
        }
        __builtin_amdgcn_sched_barrier(0);  // keep prefetch issued before compute
        #pragma unroll
        for (int i = 0; i < PFD; ++i)
            step(Age[i], Agi[i], Az[i], t + i);

        // issue loads for steps t+2*PFD .. t+3*PFD-1 into A
        #pragma unroll
        for (int i = 0; i < PFD; ++i) {
            int tp = t + 2 * PFD + i; tp = tp < T ? tp : T - 1;
            const size_t off = (size_t)tp * (size_t)N;
            Age[i] = pge[off]; Agi[i] = pgi[off]; Az[i] = pz[off];
        }
        __builtin_amdgcn_sched_barrier(0);
        #pragma unroll
        for (int i = 0; i < PFD; ++i)
            step(Bge[i], Bgi[i], Bz[i], t + PFD + i);
    }
}

extern "C" void kernel_launch(void* const* d_in, const int* in_sizes, int n_in,
                              void* d_out, int out_size, void* d_ws, size_t ws_size,
                              hipStream_t stream) {
    const float* g_exc   = (const float*)d_in[0];
    const float* g_inh   = (const float*)d_in[1];
    const float* noise   = (const float*)d_in[2];
    const float* v_th    = (const float*)d_in[3];
    const float* tau_ref = (const float*)d_in[4];

    const int N = in_sizes[3];            // 65536
    const int T = in_sizes[0] / N;        // 512

    float* out_spk = (float*)d_out;
    float* out_mem = (float*)d_out + (size_t)T * (size_t)N;

    // Constants computed in double exactly as the Python reference does.
    const double ge_decay = exp(-1.0 / 5.0);
    const double gi_decay = exp(-1.0 / 10.0);
    const double ou_alpha = exp(-1.0 / 5.0);
    const double ou_sigma = 0.02 * sqrt(1.0 - ou_alpha * ou_alpha);

    const int block = 256;
    const int grid = (N + block - 1) / block;   // 256 blocks -> 1 block/CU
    lif_scan<<<grid, block, 0, stream>>>(
        g_exc, g_inh, noise, v_th, tau_ref, out_spk, out_mem,
        N, T,
        (float)ge_decay, (float)gi_decay, (float)ou_alpha, (float)ou_sigma);
}